// Round 3
// baseline (255.713 us; speedup 1.0000x reference)
//
#include <hip/hip_runtime.h>
#include <stdint.h>

// DilatedMask fused v2: mask = (x == 0), 33x33 sliding max (SAME) == binary dilation.
// One kernel; each block = 32 output rows + 2*16 halo staged as packed bits in LDS.
// Changes vs v1 (95us, 2.8TB/s, occ 38%):
//  - TPB 512 -> 1024 (16 waves), grid 512 = exactly 2 blocks/CU = 32 waves = 100%
//    wave occupancy (__launch_bounds__(1024,8) caps VGPR at 64 to guarantee it).
//  - spread4 bit-interleave eliminated: lanes load at stride 64 so each __ballot
//    IS a raster-order 64-bit packed word (bit lane <-> px seg*256 + j*64 + lane).
//    Pack phase VALU drops ~4x (was ~80 masked ops/row/wave, the 41% VALUBusy).

#define HH 2048
#define WPX 2048
#define WW 32            // uint64 words per row (2048 bits)
#define RAD 16
#define ROWS 32          // output rows per block
#define SROWS (ROWS + 2 * RAD)   // 64 staged rows
#define TPB 1024

typedef int vint4 __attribute__((ext_vector_type(4)));

__global__ __launch_bounds__(TPB, 8) void fused_dilate_kernel(const float* __restrict__ x,
                                                              int* __restrict__ out) {
  __shared__ uint64_t stage[SROWS][WW];    // 16 KiB
  __shared__ uint64_t vall[ROWS][WW + 2];  // zero guard columns, 8.5 KiB
  __shared__ uint64_t hrow[ROWS][WW];      // 8 KiB

  // XCD-aware swizzle: 512 blocks, 8 XCDs, 64 consecutive tiles per XCD so
  // halo-sharing neighbor tiles are co-resident on one XCD's L2 (validated:
  // round-2 FETCH_SIZE == compulsory 133 MB).
  const int cpx = gridDim.x >> 3;                       // 64
  const int tile = (blockIdx.x & 7) * cpx + (blockIdx.x >> 3);
  const int gr0 = tile * ROWS;                          // 2048 % 32 == 0: never straddles images
  const int n  = gr0 >> 11;
  const int h0 = gr0 & (HH - 1);
  const float* xb = x + (long long)n * HH * WPX;

  const int t = threadIdx.x;
  const int lane = t & 63;
  const int wv = t >> 6;                                // 0..15
  const int seg = wv & 7;                               // 256-px segment within a row
  const int rwv = wv >> 3;                              // 0/1: row offset within pair

  // --- pack: 64 staged rows, 2 rows per iteration (waves 0-7 row A, 8-15 row B).
  // Lane l loads px seg*256 + j*64 + l  ->  ballot bit l is already raster order.
#pragma unroll 4
  for (int rr0 = 0; rr0 < SROWS; rr0 += 2) {
    const int rr = rr0 + rwv;
    int hh = h0 + rr - RAD;
    hh = hh < 0 ? 0 : (hh > HH - 1 ? HH - 1 : hh);      // clamp == clipped SAME (OR-idempotent)
    const float* rp = xb + (long long)hh * WPX + (seg << 8) + lane;
#pragma unroll
    for (int j = 0; j < 4; ++j) {
      const unsigned long long b = __ballot(rp[j << 6] == 0.0f);
      if (lane == (j << 4)) stage[rr][(seg << 2) + j] = b;
    }
  }
  __syncthreads();

  const int w = t & 31;
  const int r = t >> 5;                                 // 0..31, one pass

  // --- vertical OR: 33-row window from stage ---
  {
    uint64_t v = 0;
#pragma unroll
    for (int i = 0; i <= 2 * RAD; ++i) v |= stage[r + i][w];
    vall[r][w + 1] = v;
    if (w == 0) { vall[r][0] = 0; vall[r][WW + 1] = 0; }
  }
  __syncthreads();

  // --- horizontal OR: +-16 bit shifts with neighbor-word carries ---
  {
    const uint64_t p  = vall[r][w];
    const uint64_t c  = vall[r][w + 1];
    const uint64_t nx = vall[r][w + 2];
    uint64_t res = c;
#pragma unroll
    for (int s = 1; s <= RAD; ++s) {
      res |= (c >> s) | (nx << (64 - s));
      res |= (c << s) | (p >> (64 - s));
    }
    hrow[r][w] = res;
  }
  __syncthreads();

  // --- unpack + store: 32 rows x 2048 px = 16384 int4, 16/thread, coalesced, nt.
  // 16 consecutive threads read the same hrow word: LDS broadcast, conflict-free.
  int* obase = out + (long long)gr0 * WPX;
#pragma unroll
  for (int it = 0; it < ROWS * (WPX / 4) / TPB; ++it) { // 16 iters
    const int f = it * TPB + t;                         // int4 index in tile
    const int row_l = f >> 9;                           // 512 int4 per row
    const int wi = (f >> 4) & 31;                       // 16 int4 per word
    const int sh = (f & 15) * 4;
    const uint64_t bits = hrow[row_l][wi] >> sh;
    vint4 o;
    o.x = (int)(bits & 1);
    o.y = (int)((bits >> 1) & 1);
    o.z = (int)((bits >> 2) & 1);
    o.w = (int)((bits >> 3) & 1);
    __builtin_nontemporal_store(o, (vint4*)(obase + (long long)f * 4));
  }
}

extern "C" void kernel_launch(void* const* d_in, const int* in_sizes, int n_in,
                              void* d_out, int out_size, void* d_ws, size_t ws_size,
                              hipStream_t stream) {
  const float* x = (const float*)d_in[0];
  int* out = (int*)d_out;
  // 8 images * (2048/32) tiles = 512 blocks; 16 waves + 32.5 KiB LDS per block
  // -> exactly 2 blocks/CU, 32/32 waves.
  hipLaunchKernelGGL(fused_dilate_kernel, dim3(512), dim3(TPB), 0, stream, x, out);
}

// Round 4
// 223.857 us; speedup vs baseline: 1.1423x; 1.1423x over previous
//
#include <hip/hip_runtime.h>
#include <stdint.h>

// DilatedMask v3: back to the two-kernel split (fused variants measured 95-104us
// vs ~65us for the split: global phase sync means fusion gains no read/write
// overlap, and loses streaming efficiency). K1 rebuilt with the raster-order
// ballot trick (validated in rounds 2-3): lane l loads px j*64+l, so each
// __ballot IS a raster-order packed word -- spread4 bit-interleave (the 41%
// VALUBusy in v1's pack) eliminated entirely. K2 = proven baseline dilate.

#define HH_ 2048
#define WW_PX 2048
#define WW 32          // uint64 words per row (2048 bits)
#define RAD 16
#define ROWS 16        // output rows per dilate block
#define TPB2 512

typedef int vint4 __attribute__((ext_vector_type(4)));

// K1: pack. One block = one row (2048 px), 4 waves x 512 px.
// Lane l's j-th load is px seg + j*64 + l -> ballot bit l is raster order.
// 8 nt scalar loads (issued back-to-back, independent), 8 cmp/ballots,
// 8 single-lane 8B stores. No LDS, no bit-interleave VALU.
__global__ __launch_bounds__(256) void pack_kernel(const float* __restrict__ x,
                                                   uint64_t* __restrict__ packed) {
  const int t = threadIdx.x;
  const int lane = t & 63;
  const int wv = t >> 6;                       // 0..3
  const float* rp = x + (long long)blockIdx.x * WW_PX + (wv << 9) + lane;
  uint64_t* pr = packed + (long long)blockIdx.x * WW + (wv << 3);

  float v[8];
#pragma unroll
  for (int j = 0; j < 8; ++j)
    v[j] = __builtin_nontemporal_load(rp + (j << 6));
#pragma unroll
  for (int j = 0; j < 8; ++j) {
    const unsigned long long b = __ballot(v[j] == 0.0f);
    if (lane == j) pr[j] = b;                  // normal store: keep packed in cache for K2
  }
}

// K2: block = 16 output rows x 32 words (512 threads).
// Stage 48 rows (16+2*RAD halo) in LDS once, vertical OR from LDS,
// horizontal OR of +-16 bit shifts with neighbor-word carries, unpack+store.
// (Unchanged from the 225us-baseline dilate kernel.)
__global__ __launch_bounds__(TPB2) void dilate_kernel(const uint64_t* __restrict__ packed,
                                                      int* __restrict__ out) {
  __shared__ uint64_t stage[ROWS + 2 * RAD][WW];  // 48*32*8 = 12 KiB
  __shared__ uint64_t vall[ROWS][WW + 2];         // zero guard columns
  __shared__ uint64_t hrow[ROWS][WW];

  const int t = threadIdx.x;
  const int gr0 = blockIdx.x * ROWS;          // 2048 % 16 == 0: never straddles images
  const int n = gr0 >> 11;
  const int h0 = gr0 & 2047;
  const uint64_t* base = packed + (long long)n * (HH_ * WW);

  // cooperative stage: 48 rows x 32 words, coalesced (row-major), clamped
#pragma unroll
  for (int i = 0; i < (ROWS + 2 * RAD) * WW / TPB2; ++i) {
    const int idx = i * TPB2 + t;
    const int rr = idx >> 5;
    const int w_ = idx & 31;
    int hh = h0 + rr - RAD;
    hh = hh < 0 ? 0 : (hh > HH_ - 1 ? HH_ - 1 : hh);  // clamp == clipped SAME (OR-idempotent)
    stage[rr][w_] = base[hh * WW + w_];
  }
  __syncthreads();

  const int w = t & 31;
  const int r = t >> 5;                       // 0..15
  uint64_t v = 0;
#pragma unroll
  for (int i = 0; i <= 2 * RAD; ++i) v |= stage[r + i][w];
  vall[r][w + 1] = v;
  if (w == 0) { vall[r][0] = 0; vall[r][WW + 1] = 0; }
  __syncthreads();

  {
    const uint64_t p = vall[r][w];
    const uint64_t c = vall[r][w + 1];
    const uint64_t nx = vall[r][w + 2];
    uint64_t res = c;
#pragma unroll
    for (int s = 1; s <= RAD; ++s) {
      res |= (c >> s) | (nx << (64 - s));
      res |= (c << s) | (p >> (64 - s));
    }
    hrow[r][w] = res;
  }
  __syncthreads();

  // 16 rows x 2048 px = 8192 int4 stores, 16 per thread, coalesced, non-temporal
  int* obase = out + (long long)gr0 * WW_PX;
#pragma unroll
  for (int it = 0; it < 16; ++it) {
    const int f = it * TPB2 + t;         // int4 index in tile
    const int row_l = f >> 9;            // 512 int4 per row
    const int wi = (f >> 4) & 31;        // 16 int4 per word
    const int sh = (f & 15) * 4;
    const uint64_t bits = hrow[row_l][wi] >> sh;   // 16-thread same-word broadcast
    vint4 o;
    o.x = (int)(bits & 1);
    o.y = (int)((bits >> 1) & 1);
    o.z = (int)((bits >> 2) & 1);
    o.w = (int)((bits >> 3) & 1);
    __builtin_nontemporal_store(o, (vint4*)(obase + (long long)f * 4));
  }
}

extern "C" void kernel_launch(void* const* d_in, const int* in_sizes, int n_in,
                              void* d_out, int out_size, void* d_ws, size_t ws_size,
                              hipStream_t stream) {
  const float* x = (const float*)d_in[0];
  int* out = (int*)d_out;
  uint64_t* packed = (uint64_t*)d_ws;   // 8*2048*32*8 B = 4 MiB, fully rewritten every call

  // K1: 16384 rows, one block per row
  hipLaunchKernelGGL(pack_kernel, dim3(16384), dim3(256), 0, stream, x, packed);
  // K2: 16384 global rows / 16 rows per block = 1024 blocks
  hipLaunchKernelGGL(dilate_kernel, dim3(1024), dim3(TPB2), 0, stream, packed, out);
}

// Round 5
// 223.620 us; speedup vs baseline: 1.1435x; 1.0011x over previous
//
#include <hip/hip_runtime.h>
#include <stdint.h>

// DilatedMask v4: two-kernel split (proven best structure, ~72us kernel time).
// K1 unchanged from v3 (raster-order ballot pack; VALU-extreme A/B in rounds
// 0 vs 4 tied -> K1 is at its streaming floor).
// K2 rewritten barrier-light: ONE barrier (after LDS stage of 40 packed rows),
// then each wave independently does vertical OR from LDS, horizontal OR via
// __shfl within its 32-lane row group (no vall/hrow LDS, no barriers), and
// streams nt int4 stores immediately. ROWS 16->8, TPB 512->256, 2048 blocks
// = 8 blocks/CU so staging/compute/store phases of different blocks overlap
// (v3's 3-barrier lockstep serialized a read burst before the 21us write burst).

#define HH_ 2048
#define WW_PX 2048
#define WW 32          // uint64 words per row (2048 bits)
#define RAD 16
#define ROWS 8         // output rows per dilate block
#define SR (ROWS + 2 * RAD)   // 40 staged rows
#define TPB2 256

typedef int vint4 __attribute__((ext_vector_type(4)));

// K1: pack. One block = one row (2048 px), 4 waves x 512 px.
// Lane l's j-th load is px (wv*512) + j*64 + l -> ballot bit l is raster order.
// 8 independent nt loads issued upfront (MLP=8), 8 cmp/ballots, 8 one-lane stores.
__global__ __launch_bounds__(256) void pack_kernel(const float* __restrict__ x,
                                                   uint64_t* __restrict__ packed) {
  const int t = threadIdx.x;
  const int lane = t & 63;
  const int wv = t >> 6;                       // 0..3
  const float* rp = x + (long long)blockIdx.x * WW_PX + (wv << 9) + lane;
  uint64_t* pr = packed + (long long)blockIdx.x * WW + (wv << 3);

  float v[8];
#pragma unroll
  for (int j = 0; j < 8; ++j)
    v[j] = __builtin_nontemporal_load(rp + (j << 6));
#pragma unroll
  for (int j = 0; j < 8; ++j) {
    const unsigned long long b = __ballot(v[j] == 0.0f);
    if (lane == j) pr[j] = b;                  // normal store: keep packed in cache for K2
  }
}

// K2: block = 8 output rows. Stage 40 rows (8 + 2*RAD halo) in LDS once,
// then per-wave independent pipeline: 2 rows/wave (lane half h = row select,
// w = word 0..31), 33-row vertical OR from LDS, +-16-bit horizontal OR with
// neighbor-word carries fetched by __shfl, unpack 4 px/int4, nt stores.
__global__ __launch_bounds__(TPB2) void dilate_kernel(const uint64_t* __restrict__ packed,
                                                      int* __restrict__ out) {
  __shared__ uint64_t stage[SR][WW];           // 40*32*8 = 10 KiB

  const int t = threadIdx.x;
  const int gr0 = blockIdx.x * ROWS;           // 2048 % 8 == 0: never straddles images
  const int n = gr0 >> 11;
  const int h0 = gr0 & 2047;
  const uint64_t* base = packed + (long long)n * (HH_ * WW);

  // cooperative stage: 40 rows x 32 words, coalesced, row-clamped
#pragma unroll
  for (int i = 0; i < SR * WW / TPB2; ++i) {   // 5 iters
    const int idx = i * TPB2 + t;
    const int rr = idx >> 5;
    const int w_ = idx & 31;
    int hh = h0 + rr - RAD;
    hh = hh < 0 ? 0 : (hh > HH_ - 1 ? HH_ - 1 : hh);  // clamp == clipped SAME (OR-idempotent)
    stage[rr][w_] = base[hh * WW + w_];
  }
  __syncthreads();                             // the ONLY barrier

  const int lane = t & 63;
  const int wv = t >> 6;                       // 0..3
  const int w = lane & 31;                     // word index
  const int h = lane >> 5;                     // row-within-pair
  const int r = wv * 2 + h;                    // 0..7: this lane's output row

  // vertical OR: 33-row window, straight from LDS (2-way bank alias: free)
  uint64_t v = 0;
#pragma unroll
  for (int i = 0; i <= 2 * RAD; ++i) v |= stage[r + i][w];

  // horizontal OR: neighbor words via shfl within the 32-lane row group;
  // image edges get zero carries (== clipped SAME window)
  const uint64_t p  = (w == 0)  ? 0ull : __shfl(v, lane - 1);
  const uint64_t nx = (w == 31) ? 0ull : __shfl(v, lane + 1);
  uint64_t res = v;
#pragma unroll
  for (int s = 1; s <= RAD; ++s) {
    res |= (v >> s) | (nx << (64 - s));
    res |= (v << s) | (p >> (64 - s));
  }

  // unpack + store: wave owns 2 rows = 1024 int4; 16 iters, coalesced, nt.
  // Source word for int4 f lives in lane row_l*32 + wi -> one shfl per iter.
  int* optr = out + (long long)(gr0 + wv * 2) * WW_PX;
#pragma unroll
  for (int it = 0; it < 16; ++it) {
    const int f = it * 64 + lane;              // int4 index within the 2-row span
    const int row_l = f >> 9;                  // 512 int4 per row
    const int wi = (f >> 4) & 31;              // 16 int4 per word
    const int sh = (f & 15) * 4;
    const uint64_t bits = __shfl(res, row_l * 32 + wi) >> sh;
    vint4 o;
    o.x = (int)(bits & 1);
    o.y = (int)((bits >> 1) & 1);
    o.z = (int)((bits >> 2) & 1);
    o.w = (int)((bits >> 3) & 1);
    __builtin_nontemporal_store(o, (vint4*)(optr + (long long)f * 4));
  }
}

extern "C" void kernel_launch(void* const* d_in, const int* in_sizes, int n_in,
                              void* d_out, int out_size, void* d_ws, size_t ws_size,
                              hipStream_t stream) {
  const float* x = (const float*)d_in[0];
  int* out = (int*)d_out;
  uint64_t* packed = (uint64_t*)d_ws;   // 8*2048*32*8 B = 4 MiB, fully rewritten every call

  // K1: 16384 rows, one block per row
  hipLaunchKernelGGL(pack_kernel, dim3(16384), dim3(256), 0, stream, x, packed);
  // K2: 16384 global rows / 8 rows per block = 2048 blocks (8/CU, 32 waves)
  hipLaunchKernelGGL(dilate_kernel, dim3(2048), dim3(TPB2), 0, stream, packed, out);
}